// Round 1
// baseline (544.226 us; speedup 1.0000x reference)
//
#include <hip/hip_runtime.h>
#include <math.h>

#define EDIM 300
#define HDIM 300
#define LBL 5

__device__ __forceinline__ float sigmoidf_(float x) {
    return 1.0f / (1.0f + expf(-x));
}

// ---------------------------------------------------------------------------
// Kernel 1: x-projections for all nodes + fused leaf cell.
//   ixx = x@W_ix + b_ix ; fxx = x@W_fx + b_fx ; uxx = x@W_ux + b_ux
//   leaves (mask==0): c = sig(ixx+b_ih)*sig(uxx+b_uh); h = sig(fxx+b_fh)*tanh(c)
// Block: ROWS nodes, 320 threads (thread j = output column j, j<300).
// ---------------------------------------------------------------------------
template<int ROWS>
__global__ __launch_bounds__(320)
void proj_leaf_kernel(const int* __restrict__ word_ids,
                      const int* __restrict__ children_mask,
                      const float* __restrict__ emb,
                      const float* __restrict__ W_ix, const float* __restrict__ b_ix,
                      const float* __restrict__ W_fx, const float* __restrict__ b_fx,
                      const float* __restrict__ W_ux, const float* __restrict__ b_ux,
                      const float* __restrict__ b_ih, const float* __restrict__ b_fh,
                      const float* __restrict__ b_uh,
                      float* __restrict__ ixx, float* __restrict__ fxx,
                      float* __restrict__ uxx,
                      float* __restrict__ c_all, float* __restrict__ h_all,
                      int N)
{
    __shared__ float xs[ROWS][EDIM];
    const int t0 = blockIdx.x * ROWS;
    const int tid = threadIdx.x;

    // stage x rows (gather from embedding table)
    for (int idx = tid; idx < ROWS * EDIM; idx += blockDim.x) {
        int r = idx / EDIM;
        int i = idx - r * EDIM;
        int t = t0 + r;
        int w = (t < N) ? word_ids[t] : 0;
        xs[r][i] = emb[(long)w * EDIM + i];
    }
    __syncthreads();

    const int j = tid;
    if (j >= HDIM) return;

    float acc_i[ROWS], acc_f[ROWS], acc_u[ROWS];
#pragma unroll
    for (int r = 0; r < ROWS; r++) { acc_i[r] = 0.f; acc_f[r] = 0.f; acc_u[r] = 0.f; }

    for (int i = 0; i < EDIM; i++) {
        float wi = W_ix[i * HDIM + j];
        float wf = W_fx[i * HDIM + j];
        float wu = W_ux[i * HDIM + j];
#pragma unroll
        for (int r = 0; r < ROWS; r++) {
            float xv = xs[r][i];
            acc_i[r] = fmaf(xv, wi, acc_i[r]);
            acc_f[r] = fmaf(xv, wf, acc_f[r]);
            acc_u[r] = fmaf(xv, wu, acc_u[r]);
        }
    }

    const float bi = b_ix[j], bf = b_fx[j], bu = b_ux[j];
    const float bih = b_ih[j], bfh = b_fh[j], buh = b_uh[j];

#pragma unroll
    for (int r = 0; r < ROWS; r++) {
        int t = t0 + r;
        if (t >= N) break;
        float vi = acc_i[r] + bi;
        float vf = acc_f[r] + bf;
        float vu = acc_u[r] + bu;
        ixx[t * HDIM + j] = vi;
        fxx[t * HDIM + j] = vf;
        uxx[t * HDIM + j] = vu;
        int m0 = children_mask[2 * t];
        int m1 = children_mask[2 * t + 1];
        if ((m0 | m1) == 0) {  // leaf: hsum = 0, child terms = 0
            float ig = sigmoidf_(vi + bih);
            float og = sigmoidf_(vf + bfh);
            float ug = sigmoidf_(vu + buh);
            float c = ig * ug;
            float h = og * tanhf(c);
            c_all[t * HDIM + j] = c;
            h_all[t * HDIM + j] = h;
        }
    }
}

// ---------------------------------------------------------------------------
// Level kernel: one tree level (all nodes independent).
// Per node: g0 = h_c0@W_fh, g1 = h_c1@W_fh, aih = (h_c0+h_c1)@W_ih,
//           auh = (h_c0+h_c1)@W_uh  (note hsum@W_fh == g0+g1)
// then the cell:
//   i = sig(ixx + aih + b_ih); o = sig(fxx + g0+g1 + b_fh); u = sig(uxx + auh + b_uh)
//   f_k = sig(g_k + b_fh + fxx); c = i*u + f0*c_c0*m0 + f1*c_c1*m1; h = o*tanh(c)
// Block handles NPB nodes; 320 threads, thread j = output column.
// ---------------------------------------------------------------------------
template<int NPB>
__global__ __launch_bounds__(320)
void level_kernel(int level_start, int level_size,
                  const int* __restrict__ children_idx,
                  const int* __restrict__ children_mask,
                  const float* __restrict__ W_ih, const float* __restrict__ b_ih,
                  const float* __restrict__ W_fh, const float* __restrict__ b_fh,
                  const float* __restrict__ W_uh, const float* __restrict__ b_uh,
                  const float* __restrict__ ixx, const float* __restrict__ fxx,
                  const float* __restrict__ uxx,
                  float* __restrict__ c_all, float* __restrict__ h_all)
{
    __shared__ float h0s[NPB][HDIM];
    __shared__ float h1s[NPB][HDIM];
    __shared__ float msk[NPB][2];
    __shared__ int   chs[NPB][2];

    const int tid = threadIdx.x;
    const int n0 = level_start + blockIdx.x * NPB;

    if (tid < NPB * 2) {
        int r = tid >> 1, k = tid & 1;
        int c = 0; float m = 0.f;
        if (blockIdx.x * NPB + r < level_size) {
            int t = n0 + r;
            c = children_idx[2 * t + k];
            m = (float)children_mask[2 * t + k];
        }
        chs[r][k] = c;
        msk[r][k] = m;
    }
    __syncthreads();

    // stage masked child h vectors
    for (int idx = tid; idx < NPB * HDIM; idx += blockDim.x) {
        int r = idx / HDIM;
        int i = idx - r * HDIM;
        h0s[r][i] = h_all[chs[r][0] * HDIM + i] * msk[r][0];
        h1s[r][i] = h_all[chs[r][1] * HDIM + i] * msk[r][1];
    }
    __syncthreads();

    const int j = tid;
    if (j >= HDIM) return;

    float g0[NPB], g1[NPB], aih[NPB], auh[NPB];
#pragma unroll
    for (int r = 0; r < NPB; r++) { g0[r] = 0.f; g1[r] = 0.f; aih[r] = 0.f; auh[r] = 0.f; }

    for (int i = 0; i < HDIM; i++) {
        float wf = W_fh[i * HDIM + j];
        float wi = W_ih[i * HDIM + j];
        float wu = W_uh[i * HDIM + j];
#pragma unroll
        for (int r = 0; r < NPB; r++) {
            float hv0 = h0s[r][i];
            float hv1 = h1s[r][i];
            float hs = hv0 + hv1;
            g0[r]  = fmaf(hv0, wf, g0[r]);
            g1[r]  = fmaf(hv1, wf, g1[r]);
            aih[r] = fmaf(hs, wi, aih[r]);
            auh[r] = fmaf(hs, wu, auh[r]);
        }
    }

    const float bih = b_ih[j], bfh = b_fh[j], buh = b_uh[j];
#pragma unroll
    for (int r = 0; r < NPB; r++) {
        if (blockIdx.x * NPB + r >= level_size) break;
        int t = n0 + r;
        float vix = ixx[t * HDIM + j];
        float vfx = fxx[t * HDIM + j];
        float vux = uxx[t * HDIM + j];
        float ig = sigmoidf_(vix + aih[r] + bih);
        float og = sigmoidf_(vfx + g0[r] + g1[r] + bfh);
        float ug = sigmoidf_(vux + auh[r] + buh);
        float f0 = sigmoidf_(g0[r] + bfh + vfx);
        float f1 = sigmoidf_(g1[r] + bfh + vfx);
        float m0 = msk[r][0], m1 = msk[r][1];
        float cc0 = c_all[chs[r][0] * HDIM + j] * m0;
        float cc1 = c_all[chs[r][1] * HDIM + j] * m1;
        float c = ig * ug + f0 * cc0 + f1 * cc1;   // masks are 0/1 so m*m == m
        float h = og * tanhf(c);
        c_all[t * HDIM + j] = c;
        h_all[t * HDIM + j] = h;
    }
}

// ---------------------------------------------------------------------------
// Output kernel: logits = h@W_out + b_out (300->5), log_softmax, loss.
// One wave (64 lanes) per node; 5 shuffle-reductions.
// ---------------------------------------------------------------------------
__global__ __launch_bounds__(64)
void out_kernel(const float* __restrict__ h_all,
                const int* __restrict__ labels,
                const float* __restrict__ W_out, const float* __restrict__ b_out,
                float* __restrict__ out, float* __restrict__ loss, int N)
{
    const int t = blockIdx.x;
    const int l = threadIdx.x;

    float acc[LBL];
#pragma unroll
    for (int k = 0; k < LBL; k++) acc[k] = 0.f;

    for (int i = l; i < HDIM; i += 64) {
        float hv = h_all[t * HDIM + i];
#pragma unroll
        for (int k = 0; k < LBL; k++)
            acc[k] = fmaf(hv, W_out[i * LBL + k], acc[k]);
    }

#pragma unroll
    for (int k = 0; k < LBL; k++) {
        float v = acc[k];
        for (int off = 32; off > 0; off >>= 1)
            v += __shfl_down(v, off, 64);
        acc[k] = v;
    }

    if (l == 0) {
        float lg[LBL];
        float mx = -1e30f;
#pragma unroll
        for (int k = 0; k < LBL; k++) {
            lg[k] = acc[k] + b_out[k];
            mx = fmaxf(mx, lg[k]);
        }
        float s = 0.f;
#pragma unroll
        for (int k = 0; k < LBL; k++) s += expf(lg[k] - mx);
        float lse = mx + logf(s);
        int lab = labels[t];
#pragma unroll
        for (int k = 0; k < LBL; k++)
            out[t * LBL + k] = lg[k] - lse;
        atomicAdd(loss, -(lg[lab] - lse));
    }
}

// ---------------------------------------------------------------------------
extern "C" void kernel_launch(void* const* d_in, const int* in_sizes, int n_in,
                              void* d_out, int out_size, void* d_ws, size_t ws_size,
                              hipStream_t stream)
{
    const int*   word_ids      = (const int*)d_in[0];
    const int*   labels        = (const int*)d_in[1];
    const int*   children_idx  = (const int*)d_in[2];
    const int*   children_mask = (const int*)d_in[3];
    const float* emb   = (const float*)d_in[4];
    const float* W_ix  = (const float*)d_in[5];  const float* b_ix = (const float*)d_in[6];
    const float* W_ih  = (const float*)d_in[7];  const float* b_ih = (const float*)d_in[8];
    const float* W_fx  = (const float*)d_in[9];  const float* b_fx = (const float*)d_in[10];
    const float* W_fh  = (const float*)d_in[11]; const float* b_fh = (const float*)d_in[12];
    const float* W_ux  = (const float*)d_in[13]; const float* b_ux = (const float*)d_in[14];
    const float* W_uh  = (const float*)d_in[15]; const float* b_uh = (const float*)d_in[16];
    const float* W_out = (const float*)d_in[17]; const float* b_out = (const float*)d_in[18];

    const int N = in_sizes[0];

    float* out  = (float*)d_out;
    float* loss = out + (size_t)N * LBL;

    float* ws    = (float*)d_ws;
    float* ixx   = ws;
    float* fxx   = ixx + (size_t)N * HDIM;
    float* uxx   = fxx + (size_t)N * HDIM;
    float* c_all = uxx + (size_t)N * HDIM;
    float* h_all = c_all + (size_t)N * HDIM;

    hipMemsetAsync(loss, 0, sizeof(float), stream);

    constexpr int ROWS = 8;
    int nb = (N + ROWS - 1) / ROWS;
    proj_leaf_kernel<ROWS><<<nb, 320, 0, stream>>>(
        word_ids, children_mask, emb,
        W_ix, b_ix, W_fx, b_fx, W_ux, b_ux,
        b_ih, b_fh, b_uh,
        ixx, fxx, uxx, c_all, h_all, N);

    const int leaves = (N + 1) / 2;
    int prev_size = leaves;
    int start = leaves;
    while (prev_size > 1) {
        int size = prev_size / 2;
        int npb = (size >= 256) ? 4 : (size >= 128 ? 2 : 1);
        int blocks = (size + npb - 1) / npb;
        switch (npb) {
            case 4:
                level_kernel<4><<<blocks, 320, 0, stream>>>(
                    start, size, children_idx, children_mask,
                    W_ih, b_ih, W_fh, b_fh, W_uh, b_uh,
                    ixx, fxx, uxx, c_all, h_all);
                break;
            case 2:
                level_kernel<2><<<blocks, 320, 0, stream>>>(
                    start, size, children_idx, children_mask,
                    W_ih, b_ih, W_fh, b_fh, W_uh, b_uh,
                    ixx, fxx, uxx, c_all, h_all);
                break;
            default:
                level_kernel<1><<<blocks, 320, 0, stream>>>(
                    start, size, children_idx, children_mask,
                    W_ih, b_ih, W_fh, b_fh, W_uh, b_uh,
                    ixx, fxx, uxx, c_all, h_all);
                break;
        }
        prev_size = size;
        start += size;
    }

    out_kernel<<<N, 64, 0, stream>>>(h_all, labels, W_out, b_out, out, loss, N);
}

// Round 2
// 390.575 us; speedup vs baseline: 1.3934x; 1.3934x over previous
//
#include <hip/hip_runtime.h>
#include <math.h>

#define HDIM 300
#define LBL 5

__device__ __forceinline__ float sigmoidf_(float x) {
    return 1.0f / (1.0f + expf(-x));
}

// ---------------------------------------------------------------------------
// proj kernel: ixx/fxx/uxx = x@W_*x + b_*x for all nodes.
// Grid: ceil(N/ROWS) blocks. Block: 512 threads.
// Thread t (t<450): mat = t/150, col-pair jj = (t%150)*2  (float2 loads).
// x rows staged in LDS (broadcast reads in K-loop).
// ---------------------------------------------------------------------------
template<int ROWS>
__global__ __launch_bounds__(512)
void proj_kernel(const int* __restrict__ word_ids,
                 const float* __restrict__ emb,
                 const float* __restrict__ W_ix, const float* __restrict__ b_ix,
                 const float* __restrict__ W_fx, const float* __restrict__ b_fx,
                 const float* __restrict__ W_ux, const float* __restrict__ b_ux,
                 float* __restrict__ ixx, float* __restrict__ fxx,
                 float* __restrict__ uxx, int N)
{
    __shared__ float xs[ROWS][HDIM];
    const int t0 = blockIdx.x * ROWS;
    const int tid = threadIdx.x;

    for (int idx = tid; idx < ROWS * HDIM; idx += 512) {
        int r = idx / HDIM;
        int i = idx - r * HDIM;
        int t = t0 + r;
        float v = 0.f;
        if (t < N) {
            size_t w = (size_t)word_ids[t];
            v = emb[w * HDIM + i];
        }
        xs[r][i] = v;
    }
    __syncthreads();

    if (tid >= 450) return;
    const int mat = tid / 150;
    const int jj = (tid - mat * 150) * 2;

    const float* __restrict__ W = (mat == 0) ? W_ix : (mat == 1) ? W_fx : W_ux;
    const float* __restrict__ B = (mat == 0) ? b_ix : (mat == 1) ? b_fx : b_ux;
    float* __restrict__ O       = (mat == 0) ? ixx  : (mat == 1) ? fxx  : uxx;

    float a0[ROWS], a1[ROWS];
#pragma unroll
    for (int r = 0; r < ROWS; r++) { a0[r] = 0.f; a1[r] = 0.f; }

#pragma unroll 6
    for (int i = 0; i < HDIM; i++) {
        float2 w = *(const float2*)(W + (size_t)i * HDIM + jj);
#pragma unroll
        for (int r = 0; r < ROWS; r++) {
            float xv = xs[r][i];
            a0[r] = fmaf(xv, w.x, a0[r]);
            a1[r] = fmaf(xv, w.y, a1[r]);
        }
    }

    const float bb0 = B[jj], bb1 = B[jj + 1];
#pragma unroll
    for (int r = 0; r < ROWS; r++) {
        int t = t0 + r;
        if (t >= N) break;
        O[(size_t)t * HDIM + jj]     = a0[r] + bb0;
        O[(size_t)t * HDIM + jj + 1] = a1[r] + bb1;
    }
}

// ---------------------------------------------------------------------------
// Level kernel: one block per node, 960 threads = 3 groups x 5 waves.
//   group0 (tid   0..299): aih[j] = sum_i (h0+h1)[i] * W_ih[i][j]
//   group1 (tid 320..619): g0[j]  = sum_i h0[i]*W_fh[i][j];  g1[j] likewise h1
//   group2 (tid 640..939): auh[j] = sum_i (h0+h1)[i] * W_uh[i][j]
// FIRST=true: children are leaves; compute their cells from ixx/fxx/uxx here
// (leaf h written to global for out kernel; leaf c stays in LDS).
// Then group0 threads compute the parent cell.
// ---------------------------------------------------------------------------
template<bool FIRST>
__global__ __launch_bounds__(960)
void level_kernel(int level_start,
                  const int* __restrict__ children_idx,
                  const int* __restrict__ children_mask,
                  const float* __restrict__ W_ih, const float* __restrict__ b_ih,
                  const float* __restrict__ W_fh, const float* __restrict__ b_fh,
                  const float* __restrict__ W_uh, const float* __restrict__ b_uh,
                  const float* __restrict__ ixx, const float* __restrict__ fxx,
                  const float* __restrict__ uxx,
                  float* __restrict__ c_all, float* __restrict__ h_all)
{
    __shared__ float h0s[HDIM], h1s[HDIM];
    __shared__ float c0s[HDIM], c1s[HDIM];   // used only when FIRST
    __shared__ float g0s[HDIM], g1s[HDIM], aihs[HDIM], auhs[HDIM];

    const int tid = threadIdx.x;
    const int t   = level_start + blockIdx.x;

    const int c0 = children_idx[2 * t];
    const int c1 = children_idx[2 * t + 1];
    const float m0 = (float)children_mask[2 * t];
    const float m1 = (float)children_mask[2 * t + 1];

    if (FIRST) {
        // children are leaves: hsum=0 cell
        const int gid = tid / 320;
        const int j   = tid - gid * 320;
        if (gid < 2 && j < HDIM) {
            int ch = (gid == 0) ? c0 : c1;
            float m = (gid == 0) ? m0 : m1;
            size_t o = (size_t)ch * HDIM + j;
            float ig = sigmoidf_(ixx[o] + b_ih[j]);
            float og = sigmoidf_(fxx[o] + b_fh[j]);
            float ug = sigmoidf_(uxx[o] + b_uh[j]);
            float c = ig * ug;
            float h = og * tanhf(c);
            h_all[o] = h;               // unmasked, for out kernel
            if (gid == 0) { h0s[j] = h * m; c0s[j] = c * m; }
            else          { h1s[j] = h * m; c1s[j] = c * m; }
        }
    } else {
        for (int idx = tid; idx < 2 * HDIM; idx += 960) {
            int r = idx < HDIM ? 0 : 1;
            int i = idx - r * HDIM;
            int ch = r ? c1 : c0;
            float m = r ? m1 : m0;
            float hv = h_all[(size_t)ch * HDIM + i] * m;
            if (r) h1s[i] = hv; else h0s[i] = hv;
        }
    }
    __syncthreads();

    const int gid = tid / 320;
    const int j   = tid - gid * 320;
    if (j < HDIM) {
        const float* __restrict__ W = (gid == 0) ? W_ih : (gid == 1) ? W_fh : W_uh;
        float a0 = 0.f, a1 = 0.f;
#pragma unroll 6
        for (int i = 0; i < HDIM; i++) {
            float w = W[(size_t)i * HDIM + j];
            float h0 = h0s[i], h1 = h1s[i];
            if (gid == 1) {
                a0 = fmaf(h0, w, a0);
                a1 = fmaf(h1, w, a1);
            } else {
                a0 = fmaf(h0 + h1, w, a0);
            }
        }
        if (gid == 0)      aihs[j] = a0;
        else if (gid == 1) { g0s[j] = a0; g1s[j] = a1; }
        else               auhs[j] = a0;
    }
    __syncthreads();

    if (tid < HDIM) {
        const int jj = tid;
        size_t o = (size_t)t * HDIM + jj;
        float vix = ixx[o], vfx = fxx[o], vux = uxx[o];
        float g0 = g0s[jj], g1 = g1s[jj];
        float bfh = b_fh[jj];
        float ig = sigmoidf_(vix + aihs[jj] + b_ih[jj]);
        float og = sigmoidf_(vfx + g0 + g1 + bfh);
        float ug = sigmoidf_(vux + auhs[jj] + b_uh[jj]);
        float f0 = sigmoidf_(g0 + bfh + vfx);
        float f1 = sigmoidf_(g1 + bfh + vfx);
        float cc0, cc1;
        if (FIRST) { cc0 = c0s[jj]; cc1 = c1s[jj]; }
        else {
            cc0 = c_all[(size_t)c0 * HDIM + jj] * m0;
            cc1 = c_all[(size_t)c1 * HDIM + jj] * m1;
        }
        float c = ig * ug + f0 * cc0 + f1 * cc1;
        float h = og * tanhf(c);
        c_all[o] = c;
        h_all[o] = h;
    }
}

// ---------------------------------------------------------------------------
// Output kernel: logits = h@W_out + b_out (300->5), log_softmax, loss.
// One wave (64 lanes) per node.
// ---------------------------------------------------------------------------
__global__ __launch_bounds__(64)
void out_kernel(const float* __restrict__ h_all,
                const int* __restrict__ labels,
                const float* __restrict__ W_out, const float* __restrict__ b_out,
                float* __restrict__ out, float* __restrict__ loss, int N)
{
    const int t = blockIdx.x;
    const int l = threadIdx.x;

    float acc[LBL];
#pragma unroll
    for (int k = 0; k < LBL; k++) acc[k] = 0.f;

    for (int i = l; i < HDIM; i += 64) {
        float hv = h_all[(size_t)t * HDIM + i];
#pragma unroll
        for (int k = 0; k < LBL; k++)
            acc[k] = fmaf(hv, W_out[i * LBL + k], acc[k]);
    }

#pragma unroll
    for (int k = 0; k < LBL; k++) {
        float v = acc[k];
        for (int off = 32; off > 0; off >>= 1)
            v += __shfl_down(v, off, 64);
        acc[k] = v;
    }

    if (l == 0) {
        float lg[LBL];
        float mx = -1e30f;
#pragma unroll
        for (int k = 0; k < LBL; k++) {
            lg[k] = acc[k] + b_out[k];
            mx = fmaxf(mx, lg[k]);
        }
        float s = 0.f;
#pragma unroll
        for (int k = 0; k < LBL; k++) s += expf(lg[k] - mx);
        float lse = mx + logf(s);
        int lab = labels[t];
#pragma unroll
        for (int k = 0; k < LBL; k++)
            out[t * LBL + k] = lg[k] - lse;
        atomicAdd(loss, -(lg[lab] - lse));
    }
}

// ---------------------------------------------------------------------------
extern "C" void kernel_launch(void* const* d_in, const int* in_sizes, int n_in,
                              void* d_out, int out_size, void* d_ws, size_t ws_size,
                              hipStream_t stream)
{
    const int*   word_ids      = (const int*)d_in[0];
    const int*   labels        = (const int*)d_in[1];
    const int*   children_idx  = (const int*)d_in[2];
    const int*   children_mask = (const int*)d_in[3];
    const float* emb   = (const float*)d_in[4];
    const float* W_ix  = (const float*)d_in[5];  const float* b_ix = (const float*)d_in[6];
    const float* W_ih  = (const float*)d_in[7];  const float* b_ih = (const float*)d_in[8];
    const float* W_fx  = (const float*)d_in[9];  const float* b_fx = (const float*)d_in[10];
    const float* W_fh  = (const float*)d_in[11]; const float* b_fh = (const float*)d_in[12];
    const float* W_ux  = (const float*)d_in[13]; const float* b_ux = (const float*)d_in[14];
    const float* W_uh  = (const float*)d_in[15]; const float* b_uh = (const float*)d_in[16];
    const float* W_out = (const float*)d_in[17]; const float* b_out = (const float*)d_in[18];

    const int N = in_sizes[0];

    float* out  = (float*)d_out;
    float* loss = out + (size_t)N * LBL;

    float* ws    = (float*)d_ws;
    float* ixx   = ws;
    float* fxx   = ixx + (size_t)N * HDIM;
    float* uxx   = fxx + (size_t)N * HDIM;
    float* c_all = uxx + (size_t)N * HDIM;
    float* h_all = c_all + (size_t)N * HDIM;

    hipMemsetAsync(loss, 0, sizeof(float), stream);

    constexpr int ROWS = 4;
    int nb = (N + ROWS - 1) / ROWS;
    proj_kernel<ROWS><<<nb, 512, 0, stream>>>(
        word_ids, emb, W_ix, b_ix, W_fx, b_fx, W_ux, b_ux,
        ixx, fxx, uxx, N);

    const int leaves = (N + 1) / 2;
    int prev = leaves;
    int start = leaves;
    bool first = true;
    while (prev > 1) {
        int size = prev / 2;
        if (first) {
            level_kernel<true><<<size, 960, 0, stream>>>(
                start, children_idx, children_mask,
                W_ih, b_ih, W_fh, b_fh, W_uh, b_uh,
                ixx, fxx, uxx, c_all, h_all);
        } else {
            level_kernel<false><<<size, 960, 0, stream>>>(
                start, children_idx, children_mask,
                W_ih, b_ih, W_fh, b_fh, W_uh, b_uh,
                ixx, fxx, uxx, c_all, h_all);
        }
        first = false;
        prev = size;
        start += size;
    }

    out_kernel<<<N, 64, 0, stream>>>(h_all, labels, W_out, b_out, out, loss, N);
}